// Round 1
// baseline (3610.008 us; speedup 1.0000x reference)
//
#include <hip/hip_runtime.h>
#include <math.h>

// Problem constants
#define SOSIDX 2
// B=64, S=100, T=50, H=512, E=512, F=64, V=32000; T+1=51; R=51*64=3264
// d_out layout: outputs [64,51,32000] | atts [51,100,64] | hF [64,512] | cF [64,512]
#define OUT_ATT  104448000ll
#define OUT_H    104774400ll
#define OUT_C    104807168ll

// ---------------------------------------------------------------------------
// Generic 64x64-tile f32 GEMM: C = act(A[M,K] @ B[K,N] + bias)
// AMODE 0: plain A.  AMODE 1: x-gather (aux0=emb, aux1=input_embeddings).
// AMODE 2: concat gather (aux0=ctx [r,512], aux1=h_all [r,512]).
// CMODE 0: C[r*N+c].  CMODE 1: logits remap C[(b*51+t)*N+c], r=t*64+b.
// ---------------------------------------------------------------------------
template<int AMODE, int CMODE, int TANH>
__global__ __launch_bounds__(256) void gemm_k(
    const float* __restrict__ A, const float* __restrict__ Bm,
    const float* __restrict__ bias, float* __restrict__ C,
    int M, int N, int K,
    const float* __restrict__ aux0, const float* __restrict__ aux1)
{
    __shared__ float As[16][64];
    __shared__ float Bs[16][64];
    const int tid = threadIdx.x;
    const int row0 = blockIdx.y * 64, col0 = blockIdx.x * 64;
    const int la_row = tid >> 2;          // 0..63
    const int la_k   = (tid & 3) * 4;     // 0,4,8,12
    const int lb_k   = tid >> 4;          // 0..15
    const int lb_c   = (tid & 15) * 4;    // 0..60
    const int cx = tid & 15, ry = tid >> 4;

    float acc[4][4] = {};
    float4 a_reg, b_reg;

    auto loadA = [&](int k0) -> float4 {
        const int r = row0 + la_row;
        const int k = k0 + la_k;
        const float* p;
        if constexpr (AMODE == 0) {
            p = A + (size_t)r * K + k;
        } else if constexpr (AMODE == 1) {
            const int t = r >> 6, b = r & 63;
            p = (t == 0) ? (aux0 + (size_t)SOSIDX * 512 + k)
                         : (aux1 + ((size_t)b * 50 + (t - 1)) * 512 + k);
        } else {
            p = (k < 512) ? (aux0 + (size_t)r * 512 + k)
                          : (aux1 + (size_t)r * 512 + (k - 512));
        }
        return *(const float4*)p;
    };
    auto loadB = [&](int k0) -> float4 {
        return *(const float4*)(Bm + (size_t)(k0 + lb_k) * N + col0 + lb_c);
    };

    a_reg = loadA(0);
    b_reg = loadB(0);
    for (int k0 = 0;;) {
        As[la_k + 0][la_row] = a_reg.x;
        As[la_k + 1][la_row] = a_reg.y;
        As[la_k + 2][la_row] = a_reg.z;
        As[la_k + 3][la_row] = a_reg.w;
        *(float4*)&Bs[lb_k][lb_c] = b_reg;
        __syncthreads();
        const int kn = k0 + 16;
        if (kn < K) { a_reg = loadA(kn); b_reg = loadB(kn); }
#pragma unroll
        for (int kk = 0; kk < 16; kk++) {
            const float4 av = *(const float4*)&As[kk][ry * 4];
            const float4 bv = *(const float4*)&Bs[kk][cx * 4];
            const float aa[4] = {av.x, av.y, av.z, av.w};
            const float bb[4] = {bv.x, bv.y, bv.z, bv.w};
#pragma unroll
            for (int i = 0; i < 4; i++)
#pragma unroll
                for (int j = 0; j < 4; j++) acc[i][j] += aa[i] * bb[j];
        }
        k0 = kn;
        if (k0 >= K) break;
        __syncthreads();
    }

#pragma unroll
    for (int i = 0; i < 4; i++) {
        const int r = row0 + ry * 4 + i;
        float v[4];
#pragma unroll
        for (int j = 0; j < 4; j++) {
            const int c = col0 + cx * 4 + j;
            v[j] = acc[i][j];
            if (bias) v[j] += bias[c];
            if constexpr (TANH) v[j] = tanhf(v[j]);
        }
        size_t base;
        if constexpr (CMODE == 0) {
            base = (size_t)r * N + col0 + cx * 4;
        } else {
            const int t = r >> 6, b = r & 63;
            base = ((size_t)b * 51 + t) * N + col0 + cx * 4;
        }
        float4 v4 = {v[0], v[1], v[2], v[3]};
        *(float4*)&C[base] = v4;
    }
}

// ---------------------------------------------------------------------------
// One LSTM step: z = ZX_t + h_prev @ Wlh; i,j,f,o split; update c,h.
// grid = 128 blocks (4 j-columns each, x 4 gates), block = 256.
// ---------------------------------------------------------------------------
__global__ __launch_bounds__(256) void lstm_step_k(
    const float* __restrict__ ZXt,   // [64,2048] (includes bl)
    const float* __restrict__ Wlh,   // Wl + 512*2048, [512,2048]
    const float* __restrict__ h_prev,// [64,512]
    const float* __restrict__ c_prev,// [64,512]
    float* __restrict__ h_out,       // [64,512]
    float* __restrict__ c_out)       // [64,512]
{
    constexpr int KC = 32;
    __shared__ float Hs[KC][64];
    __shared__ float Ws[KC][16];
    __shared__ float Zs[64][17];
    const int tid = threadIdx.x;
    const int j0 = blockIdx.x * 4;
    const int cx = tid & 15, b4 = tid >> 4;
    const int g = cx >> 2, jj = cx & 3;
    const int ncol = g * 512 + j0 + jj;

    float acc[4] = {0.f, 0.f, 0.f, 0.f};
    for (int kc = 0; kc < 512; kc += KC) {
#pragma unroll
        for (int q = 0; q < 2; q++) {
            const int idx = tid + 256 * q;        // 512 float4s
            const int b = idx >> 3;
            const int kq = (idx & 7) * 4;
            const float4 hv = *(const float4*)&h_prev[(size_t)b * 512 + kc + kq];
            Hs[kq + 0][b] = hv.x; Hs[kq + 1][b] = hv.y;
            Hs[kq + 2][b] = hv.z; Hs[kq + 3][b] = hv.w;
        }
#pragma unroll
        for (int q = 0; q < 2; q++) {
            const int e = tid + 256 * q;          // 512 scalars
            const int kk = e >> 4, c = e & 15;
            const int n = (c >> 2) * 512 + j0 + (c & 3);
            Ws[kk][c] = Wlh[(size_t)(kc + kk) * 2048 + n];
        }
        __syncthreads();
#pragma unroll
        for (int kk = 0; kk < KC; kk++) {
            const float bv = Ws[kk][cx];
            const float4 av = *(const float4*)&Hs[kk][b4 * 4];
            acc[0] += av.x * bv; acc[1] += av.y * bv;
            acc[2] += av.z * bv; acc[3] += av.w * bv;
        }
        __syncthreads();
    }
#pragma unroll
    for (int i = 0; i < 4; i++) {
        const int b = b4 * 4 + i;
        Zs[b][cx] = acc[i] + ZXt[(size_t)b * 2048 + ncol];
    }
    __syncthreads();
    const int b = tid >> 2, j2 = tid & 3;
    const float iv = Zs[b][0 + j2], jv = Zs[b][4 + j2];
    const float fv = Zs[b][8 + j2], ov = Zs[b][12 + j2];
    const float cp = c_prev[(size_t)b * 512 + j0 + j2];
    const float sf = 1.f / (1.f + expf(-(fv + 1.f)));
    const float si = 1.f / (1.f + expf(-iv));
    const float so = 1.f / (1.f + expf(-ov));
    const float cn = sf * cp + si * tanhf(jv);
    const float hn = so * tanhf(cn);
    c_out[(size_t)b * 512 + j0 + j2] = cn;
    h_out[(size_t)b * 512 + j0 + j2] = hn;
}

// ---------------------------------------------------------------------------
// Per-(t,b) dual attention: scores, two softmaxes, combine, context.
// grid = 3264, block = 256 (4 waves).
// ---------------------------------------------------------------------------
__device__ inline float block_max(float v, float* red, int tid) {
    red[tid] = v; __syncthreads();
    for (int s = 128; s > 0; s >>= 1) {
        if (tid < s) red[tid] = fmaxf(red[tid], red[tid + s]);
        __syncthreads();
    }
    const float r = red[0]; __syncthreads(); return r;
}
__device__ inline float block_sum(float v, float* red, int tid) {
    red[tid] = v; __syncthreads();
    for (int s = 128; s > 0; s >>= 1) {
        if (tid < s) red[tid] += red[tid + s];
        __syncthreads();
    }
    const float r = red[0]; __syncthreads(); return r;
}

__global__ __launch_bounds__(256) void attn_k(
    const float* __restrict__ phi_h, const float* __restrict__ phi_f,
    const float* __restrict__ gamma, const float* __restrict__ alpha,
    const float* __restrict__ enc, float* __restrict__ ctx,
    float* __restrict__ atts)
{
    const int r = blockIdx.x;
    const int t = r >> 6, b = r & 63;
    const int tid = threadIdx.x, lane = tid & 63, wid = tid >> 6;
    __shared__ float w[104], fw[104], red[256];

    float g[8], al[8];
    const float* gp = gamma + (size_t)r * 512;
    const float* ap = alpha + (size_t)r * 512;
#pragma unroll
    for (int j = 0; j < 8; j++) { g[j] = gp[lane * 8 + j]; al[j] = ap[lane * 8 + j]; }

    for (int s = wid; s < 100; s += 4) {
        const float* ph = phi_h + ((size_t)b * 100 + s) * 512;
        const float* pf = phi_f + ((size_t)b * 100 + s) * 512;
        float a1 = 0.f, a2 = 0.f;
#pragma unroll
        for (int j = 0; j < 8; j++) {
            a1 += ph[lane * 8 + j] * g[j];
            a2 += pf[lane * 8 + j] * al[j];
        }
#pragma unroll
        for (int o = 32; o; o >>= 1) {
            a1 += __shfl_xor(a1, o);
            a2 += __shfl_xor(a2, o);
        }
        if (lane == 0) { w[s] = a1; fw[s] = a2; }
    }
    __syncthreads();

    // softmax(w)
    float v = (tid < 100) ? w[tid] : -INFINITY;
    const float mx = block_max(v, red, tid);
    float e = (tid < 100) ? expf(w[tid] - mx) : 0.f;
    const float sm = block_sum(e, red, tid);
    const float wn = e / (1e-6f + sm);
    // softmax(fw)
    float v2 = (tid < 100) ? fw[tid] : -INFINITY;
    const float mx2 = block_max(v2, red, tid);
    float e2 = (tid < 100) ? expf(fw[tid] - mx2) : 0.f;
    const float sm2 = block_sum(e2, red, tid);
    const float fwn = e2 / (1e-6f + sm2);
    // combine
    float wc = wn * fwn;
    const float smc = block_sum((tid < 100) ? wc : 0.f, red, tid);
    wc = wc / (1e-6f + smc);
    if (tid < 100) {
        w[tid] = wc;
        atts[((size_t)t * 100 + tid) * 64 + b] = wc;
    }
    __syncthreads();

    // context[h] = sum_s wc[s] * enc[b,s,h]
#pragma unroll
    for (int q = 0; q < 2; q++) {
        const int h = tid + q * 256;
        float a = 0.f;
        for (int s = 0; s < 100; s++)
            a += w[s] * enc[((size_t)b * 100 + s) * 512 + h];
        ctx[(size_t)r * 512 + h] = a;
    }
}

__global__ __launch_bounds__(256) void copy_hc_k(
    const float* __restrict__ h_last, const float* __restrict__ c_last,
    float* __restrict__ out_h, float* __restrict__ out_c)
{
    const int i = blockIdx.x * 256 + threadIdx.x; // 32768 total
    out_h[i] = h_last[i];
    out_c[i] = c_last[i];
}

// ---------------------------------------------------------------------------
extern "C" void kernel_launch(void* const* d_in, const int* in_sizes, int n_in,
                              void* d_out, int out_size, void* d_ws, size_t ws_size,
                              hipStream_t stream) {
    const float* h0   = (const float*)d_in[0];
    const float* c0   = (const float*)d_in[1];
    const float* emb  = (const float*)d_in[2];
    const float* enc  = (const float*)d_in[3];
    const float* fld  = (const float*)d_in[4];
    const float* iemb = (const float*)d_in[5];
    const float* W1 = (const float*)d_in[6];  const float* b1 = (const float*)d_in[7];
    const float* W2 = (const float*)d_in[8];  const float* b2 = (const float*)d_in[9];
    const float* W3 = (const float*)d_in[10]; const float* b3 = (const float*)d_in[11];
    const float* W4 = (const float*)d_in[12]; const float* b4 = (const float*)d_in[13];
    const float* W5 = (const float*)d_in[14]; const float* b5 = (const float*)d_in[15];
    const float* Wl = (const float*)d_in[16]; const float* bl = (const float*)d_in[17];
    const float* Wo = (const float*)d_in[18]; const float* bo = (const float*)d_in[19];
    float* out = (float*)d_out;
    float* ws  = (float*)d_ws;

    // workspace layout (floats)
    float* phi_h = ws;                               // 6400*512
    float* phi_f = phi_h + (size_t)6400 * 512;       // 6400*512
    float* ZX    = phi_f + (size_t)6400 * 512;       // 3264*2048
    float* h_all = ZX    + (size_t)3264 * 2048;      // 3264*512  ([t][b][h])
    float* c_buf = h_all + (size_t)3264 * 512;       // 64*512
    float* gam   = c_buf + (size_t)64 * 512;         // 3264*512
    float* alp   = gam   + (size_t)3264 * 512;       // 3264*512
    float* ctx   = alp   + (size_t)3264 * 512;       // 3264*512
    float* attb  = ctx   + (size_t)3264 * 512;       // 3264*512

    const dim3 blk(256);

    // phase A: parallel pre-pass
    gemm_k<0,0,1><<<dim3(8, 100), blk, 0, stream>>>(enc, W1, b1, phi_h, 6400, 512, 512, nullptr, nullptr);
    gemm_k<0,0,1><<<dim3(8, 100), blk, 0, stream>>>(fld, W4, b4, phi_f, 6400, 512, 64, nullptr, nullptr);
    gemm_k<1,0,0><<<dim3(32, 51), blk, 0, stream>>>(nullptr, Wl, bl, ZX, 3264, 2048, 512, emb, iemb);

    // phase B: sequential LSTM scan
    for (int t = 0; t < 51; t++) {
        const float* hp = (t == 0) ? h0 : h_all + (size_t)(t - 1) * 64 * 512;
        const float* cp = (t == 0) ? c0 : c_buf;
        lstm_step_k<<<128, blk, 0, stream>>>(ZX + (size_t)t * 64 * 2048,
                                             Wl + (size_t)512 * 2048,
                                             hp, cp,
                                             h_all + (size_t)t * 64 * 512, c_buf);
    }

    // phase C: parallel post-pass
    gemm_k<0,0,1><<<dim3(8, 51), blk, 0, stream>>>(h_all, W2, b2, gam, 3264, 512, 512, nullptr, nullptr);
    gemm_k<0,0,1><<<dim3(8, 51), blk, 0, stream>>>(h_all, W5, b5, alp, 3264, 512, 512, nullptr, nullptr);
    attn_k<<<3264, blk, 0, stream>>>(phi_h, phi_f, gam, alp, enc, ctx, out + OUT_ATT);
    gemm_k<2,0,0><<<dim3(8, 51), blk, 0, stream>>>(nullptr, W3, b3, attb, 3264, 512, 1024, ctx, h_all);
    gemm_k<0,1,0><<<dim3(500, 51), blk, 0, stream>>>(attb, Wo, bo, out, 3264, 32000, 512, nullptr, nullptr);
    copy_hc_k<<<128, blk, 0, stream>>>(h_all + (size_t)50 * 64 * 512, c_buf,
                                       out + OUT_H, out + OUT_C);
}